// Round 3
// baseline (199.713 us; speedup 1.0000x reference)
//
#include <hip/hip_runtime.h>
#include <math.h>

#define DET 512
#define NA  180
#define OUT 362   // floor(sqrt(512^2/2))
#define RAD 181   // OUT/2

#define NSPLIT 6        // angle partitions per (b, tile)
#define APB    30       // angles per block (NA / NSPLIT)
#define CHUNK  6        // angle lines staged per barrier
#define LSTRIDE 516     // line stride in floats (516*4 bytes, 16B-aligned lines)

// ---------------------------------------------------------------------------
// Compile-time tables (constant memory -> scalar loads, uniform indices).
// ---------------------------------------------------------------------------
constexpr double PI_D = 3.14159265358979323846;

constexpr double tsin(double x) {  // |x| <= pi/4
    double x2 = x * x;
    return x * (1.0 + x2 * (-1.0/6 + x2 * (1.0/120 + x2 * (-1.0/5040 +
               x2 * (1.0/362880 + x2 * (-1.0/39916800))))));
}
constexpr double tcos(double x) {  // |x| <= pi/4
    double x2 = x * x;
    return 1.0 + x2 * (-0.5 + x2 * (1.0/24 + x2 * (-1.0/720 +
               x2 * (1.0/40320 + x2 * (-1.0/3628800)))));
}

struct Trig { float c[NA]; float s[NA]; };
constexpr Trig make_trig() {
    Trig t{};
    constexpr double r = PI_D / 180.0;
    for (int k = 0; k < NA; ++k) {
        double c, s;
        if (k <= 45)       { c =  tcos(k * r);          s =  tsin(k * r); }
        else if (k <= 90)  { c =  tsin((90 - k) * r);   s =  tcos((90 - k) * r); }
        else if (k <= 135) { c = -tsin((k - 90) * r);   s =  tcos((k - 90) * r); }
        else               { c = -tcos((180 - k) * r);  s =  tsin((180 - k) * r); }
        t.c[k] = (float)c; t.s[k] = (float)s;
    }
    return t;
}
__device__ constexpr Trig TRIG = make_trig();

// Full signed-offset weight table for the ramp conv, padded with zeros:
//   G[m] = -2/(pi*m)^2 for odd m <= 511, else 0.  (center tap 0.5 handled
//   separately.)  Indexed by |jj - 64*t| which reaches 959.
#define GW_N 960
struct GTbl { float g[GW_N]; };
constexpr GTbl make_g() {
    GTbl t{};
    for (int m = 0; m < GW_N; ++m) {
        if ((m & 1) && m <= 511) {
            double md = (double)m;
            t.g[m] = (float)(-2.0 / (PI_D * PI_D * md * md));
        } else {
            t.g[m] = 0.0f;
        }
    }
    return t;
}
__device__ constexpr GTbl GW = make_g();

// ---------------------------------------------------------------------------
// Kernel 1: ramp filter, parity-window-shared form.
// One wave per (b, angle) line.  Lane i computes the 8 outputs d = i + 64t.
// All taps sit at odd offsets from d, and 64t is even, so all 8 outputs of a
// lane read the SAME odd-offset window positions xs[i + jj] (jj odd) with
// lane-uniform weights G[|jj - 64t|]  -> 736 ds_read_b32 per wave instead of
// 4096, weights via scalar loads.
// Output layout: ft[b][a][d] (detector contiguous per angle).
// ---------------------------------------------------------------------------
__global__ __launch_bounds__(64) void ramp_filter_kernel(
        const float* __restrict__ x, float* __restrict__ ft) {
    const int a = blockIdx.x;
    const int b = blockIdx.y;
    const int lane = threadIdx.x;   // 0..63

    __shared__ float xs[3 * DET];  // [0,512) zeros | [512,1024) data | [1024,1536) zeros

    #pragma unroll
    for (int k = 0; k < DET / 64; ++k) {
        int d = lane + 64 * k;
        xs[d]        = 0.0f;
        xs[1024 + d] = 0.0f;
        // x is (B, 1, DET, NA): column read (strided; L2-served)
        xs[512 + d]  = x[(b * DET + d) * NA + a];
    }
    __syncthreads();

    const float* p = xs + 512 + lane;

    float acc[8];
    #pragma unroll
    for (int t = 0; t < 8; ++t) acc[t] = 0.5f * p[64 * t];   // center taps

    // odd-offset sweep: jj in {-511, -509, ..., 959}
    #pragma unroll 4
    for (int jj = -511; jj <= 959; jj += 2) {
        float v = p[jj];
        #pragma unroll
        for (int t = 0; t < 8; ++t) {
            int m = jj - 64 * t;
            m = m < 0 ? -m : m;              // wave-uniform -> scalar weight
            acc[t] = fmaf(GW.g[m], v, acc[t]);
        }
    }

    float* o = ft + (b * NA + a) * DET + lane;
    #pragma unroll
    for (int t = 0; t < 8; ++t) o[64 * t] = acc[t];
}

// ---------------------------------------------------------------------------
// Kernel 2: backprojection. Grid (12,12,B*NSPLIT); 32x32 pixel tile;
// 4 pixels/thread; CHUNK angle-lines staged per barrier; trig from constant
// memory; partials combined with atomicAdd onto memset-zeroed output.
// VALU+LDS throughput-bound (R1: occupancy increase was neutral).
// ---------------------------------------------------------------------------
__device__ __forceinline__ float interp1(const float* __restrict__ L, float pos) {
    float pf = floorf(pos);
    int   i0 = (int)pf;
    float fr = pos - pf;
    float g0 = L[i0];
    float g1 = L[i0 + 1];          // L[512] is a zero sentinel
    float v  = fmaf(fr, g1 - g0, g0);
    return pos <= (float)(DET - 1) ? v : 0.0f;   // needed: pos can reach 511.97
}

__global__ __launch_bounds__(256, 8) void backproject_kernel(
        const float* __restrict__ ft, float* __restrict__ out) {
    const int bz = blockIdx.z;
    const int b  = bz / NSPLIT;
    const int sp = bz - b * NSPLIT;
    const int r0 = blockIdx.y * 32;
    const int c0 = blockIdx.x * 32;
    const int tid = threadIdx.x;
    const int tx = tid & 15;
    const int ty = tid >> 4;

    __shared__ float line[CHUNK * LSTRIDE];

    // zero sentinels at [c][512] (never overwritten by staging)
    if (tid < CHUNK) line[tid * LSTRIDE + 512] = 0.0f;

    // clamp base coordinate for guard pixels (r/c >= OUT) so their pos stays
    // in-range; their stores are guarded off below.
    const float xpr = (float)(min(r0 + ty, OUT - 1) - RAD);   // row coord
    const float ypr = (float)(min(c0 + tx, OUT - 1) - RAD);   // col coord

    float a00 = 0.0f, a01 = 0.0f, a10 = 0.0f, a11 = 0.0f;

    const float* base = ft + (b * NA + sp * APB) * DET;

    for (int rd = 0; rd < APB / CHUNK; ++rd) {
        __syncthreads();
        const float4* g = (const float4*)(base + rd * CHUNK * DET);
        #pragma unroll
        for (int k = 0; k < (CHUNK * DET / 4) / 256; ++k) {
            int j4 = tid + k * 256;                 // float4 index in chunk
            float4 v = g[j4];
            int c = j4 >> 7;                        // line within chunk
            int d = (j4 & 127) << 2;                // detector offset
            *(float4*)&line[c * LSTRIDE + d] = v;
        }
        __syncthreads();

        const int abase = sp * APB + rd * CHUNK;
        #pragma unroll
        for (int i = 0; i < CHUNK; ++i) {
            const float cv = TRIG.c[abase + i];
            const float sv = TRIG.s[abase + i];
            // pos = ypr*cos - xpr*sin + det/2
            float p00 = fmaf(ypr, cv, fmaf(xpr, -sv, 256.0f));
            float p01 = fmaf(16.0f, cv, p00);       // col+16
            float p10 = fmaf(-16.0f, sv, p00);      // row+16
            float p11 = fmaf(-16.0f, sv, p01);      // row+16, col+16
            const float* L = line + i * LSTRIDE;
            a00 += interp1(L, p00);
            a01 += interp1(L, p01);
            a10 += interp1(L, p10);
            a11 += interp1(L, p11);
        }
    }

    const float scale = (float)(PI_D / (2.0 * NA));
    const int r = r0 + ty;
    const int c = c0 + tx;
    float* ob = out + b * OUT * OUT;
    if (r < OUT) {
        if (c < OUT)      atomicAdd(&ob[r * OUT + c],      a00 * scale);
        if (c + 16 < OUT) atomicAdd(&ob[r * OUT + c + 16], a01 * scale);
    }
    if (r + 16 < OUT) {
        if (c < OUT)      atomicAdd(&ob[(r + 16) * OUT + c],      a10 * scale);
        if (c + 16 < OUT) atomicAdd(&ob[(r + 16) * OUT + c + 16], a11 * scale);
    }
}

extern "C" void kernel_launch(void* const* d_in, const int* in_sizes, int n_in,
                              void* d_out, int out_size, void* d_ws, size_t ws_size,
                              hipStream_t stream) {
    const float* x = (const float*)d_in[0];
    float* ft  = (float*)d_ws;     // B*NA*DET*4 = 1.47 MB scratch
    float* out = (float*)d_out;

    const int B = in_sizes[0] / (DET * NA);   // 4

    hipMemsetAsync(out, 0, (size_t)out_size * sizeof(float), stream);
    ramp_filter_kernel<<<dim3(NA, B), 64, 0, stream>>>(x, ft);
    backproject_kernel<<<dim3((OUT + 31) / 32, (OUT + 31) / 32, B * NSPLIT),
                         256, 0, stream>>>(ft, out);
}

// Round 4
// 171.310 us; speedup vs baseline: 1.1658x; 1.1658x over previous
//
#include <hip/hip_runtime.h>
#include <math.h>

#define DET 512
#define NA  180
#define OUT 362   // floor(sqrt(512^2/2))
#define RAD 181   // OUT/2

#define NSPLIT 6        // angle partitions per (b, tile)
#define APB    30       // angles per block (NA / NSPLIT)
#define CHUNK  6        // angle lines staged per barrier
#define LSTRIDE 516     // line stride in floats (516*4 bytes, 16B-aligned lines)

// ---------------------------------------------------------------------------
// Compile-time tables / weights.
// ---------------------------------------------------------------------------
constexpr double PI_D = 3.14159265358979323846;

constexpr double tsin(double x) {  // |x| <= pi/4
    double x2 = x * x;
    return x * (1.0 + x2 * (-1.0/6 + x2 * (1.0/120 + x2 * (-1.0/5040 +
               x2 * (1.0/362880 + x2 * (-1.0/39916800))))));
}
constexpr double tcos(double x) {  // |x| <= pi/4
    double x2 = x * x;
    return 1.0 + x2 * (-0.5 + x2 * (1.0/24 + x2 * (-1.0/720 +
               x2 * (1.0/40320 + x2 * (-1.0/3628800)))));
}

struct Trig { float c[NA]; float s[NA]; };
constexpr Trig make_trig() {
    Trig t{};
    constexpr double r = PI_D / 180.0;
    for (int k = 0; k < NA; ++k) {
        double c, s;
        if (k <= 45)       { c =  tcos(k * r);          s =  tsin(k * r); }
        else if (k <= 90)  { c =  tsin((90 - k) * r);   s =  tcos((90 - k) * r); }
        else if (k <= 135) { c = -tsin((k - 90) * r);   s =  tcos((k - 90) * r); }
        else               { c = -tcos((180 - k) * r);  s =  tsin((180 - k) * r); }
        t.c[k] = (float)c; t.s[k] = (float)s;
    }
    return t;
}
__device__ constexpr Trig TRIG = make_trig();

// Ramp weight for odd offset m (|m| <= 511): w(m) = -2/(pi*m)^2.
// Called only with compile-time-constant m inside fully-unrolled loops ->
// folds to a 32-bit literal in v_fmac_f32 (no runtime doubles, no s_load).
__host__ __device__ constexpr float rampw(int m) {
    double md = (double)(m < 0 ? -m : m);
    return (float)(-2.0 / (PI_D * PI_D * md * md));
}

// ---------------------------------------------------------------------------
// Kernel 1: ramp filter, literal-weight tap-sharing form.
// Block = 256 threads = 1 (b, angle) line.  Thread t&127 owns 4 same-parity
// outputs q, q+32, q+64, q+96 with q = (t&31) + 128*(t>>5)  (conflict-free
// lane->bank mapping).  One ds_read xs[q+r] feeds 4 FMAs with literal
// weights rampw(r-32j).  Threads <128 sweep r in [-511, 47], threads >=128
// sweep r in [49, 607]; halves combined via an LDS reduction.
// Pure-LDS inner loop (lgkmcnt has no SMEM mixed in -> pipelined ds_reads).
// ---------------------------------------------------------------------------
__global__ __launch_bounds__(256) void ramp_filter_kernel(
        const float* __restrict__ x, float* __restrict__ ft) {
    const int a   = blockIdx.x;
    const int b   = blockIdx.y;
    const int tid = threadIdx.x;        // 0..255
    const int t    = tid & 127;         // output-thread id
    const int half = tid >> 7;          // window half
    const int q = (t & 31) + 128 * (t >> 5);   // base output (covers all 512)

    __shared__ float xs[3 * DET];       // [0,512) zeros | data | [1024,1536) zeros
    __shared__ float red[4 * 128];      // half-1 partial accumulators

    // stage + zero pads (x is (B,1,DET,NA): strided column read, L2-served)
    xs[tid]        = 0.0f;
    xs[256 + tid]  = 0.0f;
    xs[1024 + tid] = 0.0f;
    xs[1280 + tid] = 0.0f;
    xs[512 + tid]  = x[(b * DET + tid) * NA + a];
    xs[768 + tid]  = x[(b * DET + 256 + tid) * NA + a];
    __syncthreads();

    const float* p = xs + 512 + q;
    float a0 = 0.0f, a1 = 0.0f, a2 = 0.0f, a3 = 0.0f;

    if (half == 0) {
        // center taps (offset 0, weight 0.5) — once, in half 0 only
        a0 = 0.5f * p[0];
        a1 = 0.5f * p[32];
        a2 = 0.5f * p[64];
        a3 = 0.5f * p[96];
        #pragma unroll
        for (int k = 0; k < 280; ++k) {
            const int r = -511 + 2 * k;          // odd, [-511, 47]
            const float v = p[r];
            if (r      >= -511 && r      <= 511) a0 = fmaf(rampw(r),      v, a0);
            if (r - 32 >= -511 && r - 32 <= 511) a1 = fmaf(rampw(r - 32), v, a1);
            if (r - 64 >= -511 && r - 64 <= 511) a2 = fmaf(rampw(r - 64), v, a2);
            if (r - 96 >= -511 && r - 96 <= 511) a3 = fmaf(rampw(r - 96), v, a3);
        }
    } else {
        #pragma unroll
        for (int k = 0; k < 280; ++k) {
            const int r = 49 + 2 * k;            // odd, [49, 607]
            const float v = p[r];
            if (r      >= -511 && r      <= 511) a0 = fmaf(rampw(r),      v, a0);
            if (r - 32 >= -511 && r - 32 <= 511) a1 = fmaf(rampw(r - 32), v, a1);
            if (r - 64 >= -511 && r - 64 <= 511) a2 = fmaf(rampw(r - 64), v, a2);
            if (r - 96 >= -511 && r - 96 <= 511) a3 = fmaf(rampw(r - 96), v, a3);
        }
        red[      t] = a0;
        red[128 + t] = a1;
        red[256 + t] = a2;
        red[384 + t] = a3;
    }
    __syncthreads();

    if (half == 0) {
        float* o = ft + (b * NA + a) * DET + q;
        o[0]  = a0 + red[      t];
        o[32] = a1 + red[128 + t];
        o[64] = a2 + red[256 + t];
        o[96] = a3 + red[384 + t];
    }
}

// ---------------------------------------------------------------------------
// Kernel 2: backprojection (unchanged from R1). Grid (12,12,B*NSPLIT);
// 32x32 pixel tile; 4 pixels/thread; CHUNK angle-lines staged per barrier;
// trig from constant memory; atomicAdd onto memset-zeroed output.
// ---------------------------------------------------------------------------
__device__ __forceinline__ float interp1(const float* __restrict__ L, float pos) {
    float pf = floorf(pos);
    int   i0 = (int)pf;
    float fr = pos - pf;
    float g0 = L[i0];
    float g1 = L[i0 + 1];          // L[512] is a zero sentinel
    float v  = fmaf(fr, g1 - g0, g0);
    return pos <= (float)(DET - 1) ? v : 0.0f;   // pos can reach 511.97
}

__global__ __launch_bounds__(256, 8) void backproject_kernel(
        const float* __restrict__ ft, float* __restrict__ out) {
    const int bz = blockIdx.z;
    const int b  = bz / NSPLIT;
    const int sp = bz - b * NSPLIT;
    const int r0 = blockIdx.y * 32;
    const int c0 = blockIdx.x * 32;
    const int tid = threadIdx.x;
    const int tx = tid & 15;
    const int ty = tid >> 4;

    __shared__ float line[CHUNK * LSTRIDE];

    // zero sentinels at [c][512] (never overwritten by staging)
    if (tid < CHUNK) line[tid * LSTRIDE + 512] = 0.0f;

    // clamp base coordinate for guard pixels (r/c >= OUT) so their pos stays
    // in-range; their stores are guarded off below.
    const float xpr = (float)(min(r0 + ty, OUT - 1) - RAD);   // row coord
    const float ypr = (float)(min(c0 + tx, OUT - 1) - RAD);   // col coord

    float a00 = 0.0f, a01 = 0.0f, a10 = 0.0f, a11 = 0.0f;

    const float* base = ft + (b * NA + sp * APB) * DET;

    for (int rd = 0; rd < APB / CHUNK; ++rd) {
        __syncthreads();
        const float4* g = (const float4*)(base + rd * CHUNK * DET);
        #pragma unroll
        for (int k = 0; k < (CHUNK * DET / 4) / 256; ++k) {
            int j4 = tid + k * 256;                 // float4 index in chunk
            float4 v = g[j4];
            int c = j4 >> 7;                        // line within chunk
            int d = (j4 & 127) << 2;                // detector offset
            *(float4*)&line[c * LSTRIDE + d] = v;
        }
        __syncthreads();

        const int abase = sp * APB + rd * CHUNK;
        #pragma unroll
        for (int i = 0; i < CHUNK; ++i) {
            const float cv = TRIG.c[abase + i];
            const float sv = TRIG.s[abase + i];
            // pos = ypr*cos - xpr*sin + det/2
            float p00 = fmaf(ypr, cv, fmaf(xpr, -sv, 256.0f));
            float p01 = fmaf(16.0f, cv, p00);       // col+16
            float p10 = fmaf(-16.0f, sv, p00);      // row+16
            float p11 = fmaf(-16.0f, sv, p01);      // row+16, col+16
            const float* L = line + i * LSTRIDE;
            a00 += interp1(L, p00);
            a01 += interp1(L, p01);
            a10 += interp1(L, p10);
            a11 += interp1(L, p11);
        }
    }

    const float scale = (float)(PI_D / (2.0 * NA));
    const int r = r0 + ty;
    const int c = c0 + tx;
    float* ob = out + b * OUT * OUT;
    if (r < OUT) {
        if (c < OUT)      atomicAdd(&ob[r * OUT + c],      a00 * scale);
        if (c + 16 < OUT) atomicAdd(&ob[r * OUT + c + 16], a01 * scale);
    }
    if (r + 16 < OUT) {
        if (c < OUT)      atomicAdd(&ob[(r + 16) * OUT + c],      a10 * scale);
        if (c + 16 < OUT) atomicAdd(&ob[(r + 16) * OUT + c + 16], a11 * scale);
    }
}

extern "C" void kernel_launch(void* const* d_in, const int* in_sizes, int n_in,
                              void* d_out, int out_size, void* d_ws, size_t ws_size,
                              hipStream_t stream) {
    const float* x = (const float*)d_in[0];
    float* ft  = (float*)d_ws;     // B*NA*DET*4 = 1.47 MB scratch
    float* out = (float*)d_out;

    const int B = in_sizes[0] / (DET * NA);   // 4

    hipMemsetAsync(out, 0, (size_t)out_size * sizeof(float), stream);
    ramp_filter_kernel<<<dim3(NA, B), 256, 0, stream>>>(x, ft);
    backproject_kernel<<<dim3((OUT + 31) / 32, (OUT + 31) / 32, B * NSPLIT),
                         256, 0, stream>>>(ft, out);
}

// Round 5
// 98.489 us; speedup vs baseline: 2.0278x; 1.7394x over previous
//
#include <hip/hip_runtime.h>
#include <math.h>

#define DET 512
#define NA  180
#define OUT 362   // floor(sqrt(512^2/2))
#define RAD 181   // OUT/2

#define NSPLIT 6        // angle partitions per (b, tile)
#define APB    30       // angles per block (NA / NSPLIT)
#define CHUNK  6        // angle lines staged per barrier
#define LSTRIDE 516     // line stride in floats (516*4 bytes, 16B-aligned lines)

// ---------------------------------------------------------------------------
// Compile-time tables / weights.
// ---------------------------------------------------------------------------
constexpr double PI_D = 3.14159265358979323846;

constexpr double tsin(double x) {  // |x| <= pi/4
    double x2 = x * x;
    return x * (1.0 + x2 * (-1.0/6 + x2 * (1.0/120 + x2 * (-1.0/5040 +
               x2 * (1.0/362880 + x2 * (-1.0/39916800))))));
}
constexpr double tcos(double x) {  // |x| <= pi/4
    double x2 = x * x;
    return 1.0 + x2 * (-0.5 + x2 * (1.0/24 + x2 * (-1.0/720 +
               x2 * (1.0/40320 + x2 * (-1.0/3628800)))));
}

struct Trig { float c[NA]; float s[NA]; };
constexpr Trig make_trig() {
    Trig t{};
    constexpr double r = PI_D / 180.0;
    for (int k = 0; k < NA; ++k) {
        double c, s;
        if (k <= 45)       { c =  tcos(k * r);          s =  tsin(k * r); }
        else if (k <= 90)  { c =  tsin((90 - k) * r);   s =  tcos((90 - k) * r); }
        else if (k <= 135) { c = -tsin((k - 90) * r);   s =  tcos((k - 90) * r); }
        else               { c = -tcos((180 - k) * r);  s =  tsin((180 - k) * r); }
        t.c[k] = (float)c; t.s[k] = (float)s;
    }
    return t;
}
__device__ constexpr Trig TRIG = make_trig();

// Ramp weight for odd offset m: w(m) = -2/(pi*m)^2; 0 outside [-511,511] or
// for even m.  ONLY used in constexpr context (template args / if constexpr)
// so it is guaranteed to fold to a 32-bit float literal — R4's failure was
// this function evaluating at RUNTIME in f64 (18k VALU instr/wave, 90 us).
__host__ __device__ constexpr float rampw0(int m) {
    int a = m < 0 ? -m : m;
    if (a > 511 || (a & 1) == 0) return 0.0f;
    double md = (double)a;
    return (float)(-2.0 / (PI_D * PI_D * md * md));
}

// One tap: v = p[R] feeds the 4 accumulators with compile-time weights.
template<int R>
__device__ __forceinline__ void tap(const float* __restrict__ p,
        float& a0, float& a1, float& a2, float& a3) {
    const float v = p[R];
    if constexpr (rampw0(R)      != 0.0f) a0 = fmaf(rampw0(R),      v, a0);
    if constexpr (rampw0(R - 32) != 0.0f) a1 = fmaf(rampw0(R - 32), v, a1);
    if constexpr (rampw0(R - 64) != 0.0f) a2 = fmaf(rampw0(R - 64), v, a2);
    if constexpr (rampw0(R - 96) != 0.0f) a3 = fmaf(rampw0(R - 96), v, a3);
}

// Straight-line sweep over odd offsets R, R+2, ..., REND (template recursion:
// guaranteed full unroll, no runtime induction variable).
template<int R, int REND>
__device__ __forceinline__ void sweep(const float* __restrict__ p,
        float& a0, float& a1, float& a2, float& a3) {
    if constexpr (R <= REND) {
        tap<R>(p, a0, a1, a2, a3);
        sweep<R + 2, REND>(p, a0, a1, a2, a3);
    }
}

// ---------------------------------------------------------------------------
// Kernel 1: ramp filter, literal-weight tap-sharing form.
// Block = 256 threads = 1 (b, angle) line.  Thread t=tid&127 owns 4
// same-parity outputs q, q+32, q+64, q+96, q = (t&31) + 128*(t>>5)
// (conflict-free lane->bank mapping).  One ds_read xs[q+R] feeds 4 FMAs with
// literal weights.  Threads <128 sweep R in [-511,47], threads >=128 sweep
// [49,607]; halves combined via an LDS reduction.  Pure-LDS inner loop.
// ---------------------------------------------------------------------------
__global__ __launch_bounds__(256) void ramp_filter_kernel(
        const float* __restrict__ x, float* __restrict__ ft) {
    const int a   = blockIdx.x;
    const int b   = blockIdx.y;
    const int tid = threadIdx.x;        // 0..255
    const int t    = tid & 127;         // output-thread id
    const int half = tid >> 7;          // window half
    const int q = (t & 31) + 128 * (t >> 5);   // base output (covers all 512)

    __shared__ float xs[3 * DET];       // [0,512) zeros | data | [1024,1536) zeros
    __shared__ float red[4 * 128];      // half-1 partial accumulators

    // stage + zero pads (x is (B,1,DET,NA): strided column read, L2-served)
    xs[tid]        = 0.0f;
    xs[256 + tid]  = 0.0f;
    xs[1024 + tid] = 0.0f;
    xs[1280 + tid] = 0.0f;
    xs[512 + tid]  = x[(b * DET + tid) * NA + a];
    xs[768 + tid]  = x[(b * DET + 256 + tid) * NA + a];
    __syncthreads();

    const float* p = xs + 512 + q;
    float a0 = 0.0f, a1 = 0.0f, a2 = 0.0f, a3 = 0.0f;

    if (half == 0) {
        // center taps (offset 0, weight 0.5) — once, in half 0 only
        a0 = 0.5f * p[0];
        a1 = 0.5f * p[32];
        a2 = 0.5f * p[64];
        a3 = 0.5f * p[96];
        sweep<-511, 47>(p, a0, a1, a2, a3);
    } else {
        sweep<49, 607>(p, a0, a1, a2, a3);
        red[      t] = a0;
        red[128 + t] = a1;
        red[256 + t] = a2;
        red[384 + t] = a3;
    }
    __syncthreads();

    if (half == 0) {
        float* o = ft + (b * NA + a) * DET + q;
        o[0]  = a0 + red[      t];
        o[32] = a1 + red[128 + t];
        o[64] = a2 + red[256 + t];
        o[96] = a3 + red[384 + t];
    }
}

// ---------------------------------------------------------------------------
// Kernel 2: backprojection (unchanged). Grid (12,12,B*NSPLIT); 32x32 pixel
// tile; 4 pixels/thread; CHUNK angle-lines staged per barrier; trig from
// constant memory; atomicAdd onto memset-zeroed output.
// ---------------------------------------------------------------------------
__device__ __forceinline__ float interp1(const float* __restrict__ L, float pos) {
    float pf = floorf(pos);
    int   i0 = (int)pf;
    float fr = pos - pf;
    float g0 = L[i0];
    float g1 = L[i0 + 1];          // L[512] is a zero sentinel
    float v  = fmaf(fr, g1 - g0, g0);
    return pos <= (float)(DET - 1) ? v : 0.0f;   // pos can reach 511.97
}

__global__ __launch_bounds__(256, 8) void backproject_kernel(
        const float* __restrict__ ft, float* __restrict__ out) {
    const int bz = blockIdx.z;
    const int b  = bz / NSPLIT;
    const int sp = bz - b * NSPLIT;
    const int r0 = blockIdx.y * 32;
    const int c0 = blockIdx.x * 32;
    const int tid = threadIdx.x;
    const int tx = tid & 15;
    const int ty = tid >> 4;

    __shared__ float line[CHUNK * LSTRIDE];

    // zero sentinels at [c][512] (never overwritten by staging)
    if (tid < CHUNK) line[tid * LSTRIDE + 512] = 0.0f;

    // clamp base coordinate for guard pixels (r/c >= OUT) so their pos stays
    // in-range; their stores are guarded off below.
    const float xpr = (float)(min(r0 + ty, OUT - 1) - RAD);   // row coord
    const float ypr = (float)(min(c0 + tx, OUT - 1) - RAD);   // col coord

    float a00 = 0.0f, a01 = 0.0f, a10 = 0.0f, a11 = 0.0f;

    const float* base = ft + (b * NA + sp * APB) * DET;

    for (int rd = 0; rd < APB / CHUNK; ++rd) {
        __syncthreads();
        const float4* g = (const float4*)(base + rd * CHUNK * DET);
        #pragma unroll
        for (int k = 0; k < (CHUNK * DET / 4) / 256; ++k) {
            int j4 = tid + k * 256;                 // float4 index in chunk
            float4 v = g[j4];
            int c = j4 >> 7;                        // line within chunk
            int d = (j4 & 127) << 2;                // detector offset
            *(float4*)&line[c * LSTRIDE + d] = v;
        }
        __syncthreads();

        const int abase = sp * APB + rd * CHUNK;
        #pragma unroll
        for (int i = 0; i < CHUNK; ++i) {
            const float cv = TRIG.c[abase + i];
            const float sv = TRIG.s[abase + i];
            // pos = ypr*cos - xpr*sin + det/2
            float p00 = fmaf(ypr, cv, fmaf(xpr, -sv, 256.0f));
            float p01 = fmaf(16.0f, cv, p00);       // col+16
            float p10 = fmaf(-16.0f, sv, p00);      // row+16
            float p11 = fmaf(-16.0f, sv, p01);      // row+16, col+16
            const float* L = line + i * LSTRIDE;
            a00 += interp1(L, p00);
            a01 += interp1(L, p01);
            a10 += interp1(L, p10);
            a11 += interp1(L, p11);
        }
    }

    const float scale = (float)(PI_D / (2.0 * NA));
    const int r = r0 + ty;
    const int c = c0 + tx;
    float* ob = out + b * OUT * OUT;
    if (r < OUT) {
        if (c < OUT)      atomicAdd(&ob[r * OUT + c],      a00 * scale);
        if (c + 16 < OUT) atomicAdd(&ob[r * OUT + c + 16], a01 * scale);
    }
    if (r + 16 < OUT) {
        if (c < OUT)      atomicAdd(&ob[(r + 16) * OUT + c],      a10 * scale);
        if (c + 16 < OUT) atomicAdd(&ob[(r + 16) * OUT + c + 16], a11 * scale);
    }
}

extern "C" void kernel_launch(void* const* d_in, const int* in_sizes, int n_in,
                              void* d_out, int out_size, void* d_ws, size_t ws_size,
                              hipStream_t stream) {
    const float* x = (const float*)d_in[0];
    float* ft  = (float*)d_ws;     // B*NA*DET*4 = 1.47 MB scratch
    float* out = (float*)d_out;

    const int B = in_sizes[0] / (DET * NA);   // 4

    hipMemsetAsync(out, 0, (size_t)out_size * sizeof(float), stream);
    ramp_filter_kernel<<<dim3(NA, B), 256, 0, stream>>>(x, ft);
    backproject_kernel<<<dim3((OUT + 31) / 32, (OUT + 31) / 32, B * NSPLIT),
                         256, 0, stream>>>(ft, out);
}